// Round 7
// baseline (1858.659 us; speedup 1.0000x reference)
//
#include <hip/hip_runtime.h>
#include <math.h>

// Problem constants (from reference)
#define TT 2048
#define BB 512
#define II 11
#define HH 33
#define NL 3
#define OO 18
#define SS 8                    // timesteps per epoch (barrier interval)
#define EPT (TT / SS)           // 256 working epochs per layer
#define NEP (EPT + NL - 1)      // 258 total epochs (pipeline fill/drain)
#define HROW 40                 // halves per LDS row (80 B; 34-half reads fit)

typedef _Float16 h2 __attribute__((ext_vector_type(2)));
typedef _Float16 h8 __attribute__((ext_vector_type(8)));   // 16 B -> ds_read_b128

// fast sigmoid / tanh via v_exp_f32 + v_rcp_f32 (saturate correctly at +-inf)
__device__ __forceinline__ float sigm_f(float x) {
    float e = __expf(-x);
    return __builtin_amdgcn_rcpf(1.0f + e);
}
__device__ __forceinline__ float tanh_f(float x) {
    float e = __expf(2.0f * x);
    return 1.0f - 2.0f * __builtin_amdgcn_rcpf(e + 1.0f);
}

// guarded fp32->fp16 row-slice loads (zero-pad past rem)
__device__ __forceinline__ h8 gldh8(const float* p, int k0, int rem) {
    h8 v;
    #pragma unroll
    for (int i = 0; i < 8; ++i) v[i] = (_Float16)((k0 + i < rem) ? p[k0 + i] : 0.0f);
    return v;
}
__device__ __forceinline__ h2 gldh2(const float* p, int k0, int rem) {
    h2 v;
    v.x = (_Float16)((k0 + 0 < rem) ? p[k0 + 0] : 0.0f);
    v.y = (_Float16)((k0 + 1 < rem) ? p[k0 + 1] : 0.0f);
    return v;
}

// v_dot2_f32_f16: 2 MACs/op, fp32 accumulate
#define FD(a, p, q) a = __builtin_amdgcn_fdot2((p), (q), a, false)
// one h8 slice of a vector against all 4 gate rows: 4 chains, 8cy dep spacing
#define DQ4(v, w0, w1, w2, w3) do { \
    FD(a0,(v).s01,(w0).s01); FD(a1,(v).s01,(w1).s01); FD(a2,(v).s01,(w2).s01); FD(a3,(v).s01,(w3).s01); \
    FD(a0,(v).s23,(w0).s23); FD(a1,(v).s23,(w1).s23); FD(a2,(v).s23,(w2).s23); FD(a3,(v).s23,(w3).s23); \
    FD(a0,(v).s45,(w0).s45); FD(a1,(v).s45,(w1).s45); FD(a2,(v).s45,(w2).s45); FD(a3,(v).s45,(w3).s45); \
    FD(a0,(v).s67,(w0).s67); FD(a1,(v).s67,(w1).s67); FD(a2,(v).s67,(w2).s67); FD(a3,(v).s67,(w3).s67); \
} while (0)

// EPOCH-BARRIER LSTM. Cross-round model fit (R0-R6): step = nominal MAC issue
// + a CONSTANT ~960 cy -- the per-timestep cross-SIMD sync fabric (ds_write
// drain + s_barrier + skew + post-barrier ds_read latency + trans tail).
// 2050 barriers were the bottleneck, not the MACs. Structural fix:
//   * one WAVE per layer (33 units fit in 64 lanes). The tight intra-layer
//     recurrence h(t-1)->h(t) stays INSIDE one wave: LDS ops from a wave are
//     processed in order, so write->read needs only lgkmcnt (compiler emits
//     it) -- NO barrier in the steady state.
//   * inter-layer handoff is batched: epochs of S=8 timesteps; layer l in
//     epoch e computes t in [(e-l)S, (e-l+1)S), reading layer l-1's h written
//     last epoch into a parity ping-pong buffer. ONE barrier per epoch: 258
//     barriers instead of 2050.
//   * wave0 lanes 33..54 prefetch next epoch's x (22 coalesced float4);
//     vmcnt drained once per epoch before the barrier -- off the step path.
//   * per step: input-phase dots (vi, prefetched from the stable buffer
//     mid-previous-step) run first so the own-h write->read LDS latency
//     hides under them; then own-phase dots; R4's proven tail.
// grid = 512 blocks (one batch element), block = 192 threads (3 waves).
__global__ __launch_bounds__(192, 1) void lstm_epoch_kernel(
    const float* __restrict__ x,
    const float* __restrict__ Wih0, const float* __restrict__ Whh0,
    const float* __restrict__ bih0, const float* __restrict__ bhh0,
    const float* __restrict__ Wih1, const float* __restrict__ Whh1,
    const float* __restrict__ bih1, const float* __restrict__ bhh1,
    const float* __restrict__ Wih2, const float* __restrict__ Whh2,
    const float* __restrict__ bih2, const float* __restrict__ bhh2,
    const float* __restrict__ W1, const float* __restrict__ b1,
    const float* __restrict__ W2, const float* __restrict__ b2,
    float* __restrict__ hidden_out,   // [3, 512, 33]
    float* __restrict__ outp)         // [3, 512, 18]
{
    __shared__ __align__(16) _Float16 xbuf[2][SS][HROW];      // x epoch ping-pong
    __shared__ __align__(16) _Float16 ibuf[2][2][SS][HROW];   // [par][edge l->l+1]
    __shared__ __align__(16) _Float16 hown[NL][HROW];         // own-h broadcast
    __shared__ float hfin[NL][HH + 1];
    __shared__ float h1s[NL][4 * OO];

    const int tid  = threadIdx.x;
    const int bg   = blockIdx.x;
    const int lane = tid & 63;
    const int wid  = tid >> 6;          // layer of this wave (0..2)
    const int j    = lane;              // unit within layer
    const bool cl  = (lane < HH);       // compute lane

    // ---- zero LDS comm buffers (pads stay zero forever) ----
    for (int f = tid; f < 2 * SS * HROW; f += 192) ((_Float16*)xbuf)[f] = (_Float16)0.0f;
    for (int f = tid; f < 2 * 2 * SS * HROW; f += 192) ((_Float16*)ibuf)[f] = (_Float16)0.0f;
    for (int f = tid; f < NL * HROW; f += 192) ((_Float16*)hown)[f] = (_Float16)0.0f;

    // ---- per-lane weights: 4 gates x (input 34 + own 34) halves (R4 form) ----
    h8 z8 = {0,0,0,0,0,0,0,0};
    h2 z2 = {(_Float16)0.0f, (_Float16)0.0f};
    h8 x00=z8,x01=z8,x02=z8,x03=z8; h2 x0t=z2;   // gate i, input side
    h8 x10=z8,x11=z8,x12=z8,x13=z8; h2 x1t=z2;   // gate f
    h8 x20=z8,x21=z8,x22=z8,x23=z8; h2 x2t=z2;   // gate g
    h8 x30=z8,x31=z8,x32=z8,x33=z8; h2 x3t=z2;   // gate o
    h8 h00=z8,h01=z8,h02=z8,h03=z8; h2 h0t=z2;   // own-h side
    h8 h10=z8,h11=z8,h12=z8,h13=z8; h2 h1t=z2;
    h8 h20=z8,h21=z8,h22=z8,h23=z8; h2 h2t=z2;
    h8 h30=z8,h31=z8,h32=z8,h33=z8; h2 h3t=z2;
    float b0 = 0.0f, b1v = 0.0f, b2v = 0.0f, b3v = 0.0f;

    if (cl) {
        const int l = wid;
        const float* bip = (l == 0) ? bih0 : (l == 1) ? bih1 : bih2;
        const float* bhp = (l == 0) ? bhh0 : (l == 1) ? bhh1 : bhh2;
        b0  = bip[0 * HH + j] + bhp[0 * HH + j];
        b1v = bip[1 * HH + j] + bhp[1 * HH + j];
        b2v = bip[2 * HH + j] + bhp[2 * HH + j];
        b3v = bip[3 * HH + j] + bhp[3 * HH + j];

        const float* Wi = (l == 0) ? Wih0 : (l == 1) ? Wih1 : Wih2;
        const float* Wh = (l == 0) ? Whh0 : (l == 1) ? Whh1 : Whh2;
        const int kin = (l == 0) ? II : HH;
        const float* r0 = Wi + (0 * HH + j) * kin;
        const float* r1 = Wi + (1 * HH + j) * kin;
        const float* r2 = Wi + (2 * HH + j) * kin;
        const float* r3 = Wi + (3 * HH + j) * kin;
        x00=gldh8(r0,0,kin); x01=gldh8(r0,8,kin); x02=gldh8(r0,16,kin); x03=gldh8(r0,24,kin); x0t=gldh2(r0,32,kin);
        x10=gldh8(r1,0,kin); x11=gldh8(r1,8,kin); x12=gldh8(r1,16,kin); x13=gldh8(r1,24,kin); x1t=gldh2(r1,32,kin);
        x20=gldh8(r2,0,kin); x21=gldh8(r2,8,kin); x22=gldh8(r2,16,kin); x23=gldh8(r2,24,kin); x2t=gldh2(r2,32,kin);
        x30=gldh8(r3,0,kin); x31=gldh8(r3,8,kin); x32=gldh8(r3,16,kin); x33=gldh8(r3,24,kin); x3t=gldh2(r3,32,kin);
        const float* s0 = Wh + (0 * HH + j) * HH;
        const float* s1 = Wh + (1 * HH + j) * HH;
        const float* s2 = Wh + (2 * HH + j) * HH;
        const float* s3 = Wh + (3 * HH + j) * HH;
        h00=gldh8(s0,0,HH); h01=gldh8(s0,8,HH); h02=gldh8(s0,16,HH); h03=gldh8(s0,24,HH); h0t=gldh2(s0,32,HH);
        h10=gldh8(s1,0,HH); h11=gldh8(s1,8,HH); h12=gldh8(s1,16,HH); h13=gldh8(s1,24,HH); h1t=gldh2(s1,32,HH);
        h20=gldh8(s2,0,HH); h21=gldh8(s2,8,HH); h22=gldh8(s2,16,HH); h23=gldh8(s2,24,HH); h2t=gldh2(s2,32,HH);
        h30=gldh8(s3,0,HH); h31=gldh8(s3,8,HH); h32=gldh8(s3,16,HH); h33=gldh8(s3,24,HH); h3t=gldh2(s3,32,HH);
    }

    // ---- x prefetch lanes: wave0 lanes 33..54, 22 coalesced float4 / epoch ----
    const int  pl   = lane - HH;                  // 0..21 valid
    const bool pfl  = (wid == 0) && (pl >= 0) && (pl < 22);
    const float* xblk = x + (size_t)bg * TT * II;

    // prologue: stage epoch-0 x (t = 0..7)
    if (pfl) {
        const float4 v = *(const float4*)(xblk + 4 * pl);
        #pragma unroll
        for (int q = 0; q < 4; ++q) {
            const int f = 4 * pl + q;                 // 0..87
            const int t = (f * 373) >> 12;            // f / 11 (exact for f<88)
            const int i = f - 11 * t;
            xbuf[0][t][i] = (_Float16)((&v.x)[q]);
        }
    }
    __syncthreads();

    // ---- steady state ----
    float c = 0.0f;
    const _Float16* inbase[2];
    if (wid == 0) { inbase[0] = &xbuf[0][0][0];         inbase[1] = &xbuf[1][0][0]; }
    else          { inbase[0] = &ibuf[0][wid - 1][0][0]; inbase[1] = &ibuf[1][wid - 1][0][0]; }
    const int oe = (wid < 2) ? wid : 0;               // edge index (unused for l=2)
    _Float16* outb[2] = { &ibuf[1][oe][0][0], &ibuf[0][oe][0][0] };   // write par^1
    _Float16* hop = &hown[wid][0];
    const bool haveout = (wid < 2);

    h8 vi0, vi1, vi2, vi3; h2 vit;
    h8 vo0, vo1, vo2, vo3; h2 vot;

    for (int e = 0; e < NEP; ++e) {
        const int par = e & 1;

        // A) issue x prefetch for epoch e+1 (latency hidden under 8 steps)
        float4 pv;
        const bool pf = pfl && (e < EPT - 1);
        if (pf) pv = *(const float4*)(xblk + (size_t)(e + 1) * (SS * II) + 4 * pl);

        // B) compute epoch (wave-uniform activity)
        const bool act = (e >= wid) && (e - wid < EPT);
        if (act) {
            const _Float16* inb  = inbase[par];
            _Float16*       ob   = outb[par];
            const bool      last = (e == EPT - 1 + wid);

            // epoch-top loads (once per 8 steps)
            vi0 = ((const h8*)inb)[0]; vi1 = ((const h8*)inb)[1];
            vi2 = ((const h8*)inb)[2]; vi3 = ((const h8*)inb)[3];
            vit = *(const h2*)(inb + 32);
            vo0 = ((const h8*)hop)[0]; vo1 = ((const h8*)hop)[1];
            vo2 = ((const h8*)hop)[2]; vo3 = ((const h8*)hop)[3];
            vot = *(const h2*)(hop + 32);

            auto step = [&](int k) __attribute__((always_inline)) {
                float a0 = b0, a1 = b1v, a2 = b2v, a3 = b3v;
                // phase 1: input side (vi ready -> covers own-h write->read lat)
                DQ4(vi0, x00, x10, x20, x30);
                DQ4(vi1, x01, x11, x21, x31);
                DQ4(vi2, x02, x12, x22, x32);
                DQ4(vi3, x03, x13, x23, x33);
                FD(a0, vit, x0t); FD(a1, vit, x1t);
                FD(a2, vit, x2t); FD(a3, vit, x3t);
                // phase 2: own-h side
                DQ4(vo0, h00, h10, h20, h30);
                DQ4(vo1, h01, h11, h21, h31);
                DQ4(vo2, h02, h12, h22, h32);
                DQ4(vo3, h03, h13, h23, h33);
                FD(a0, vot, h0t); FD(a1, vot, h1t);
                FD(a2, vot, h2t); FD(a3, vot, h3t);
                // prefetch next step's input vector (stable epoch buffer)
                if (k < SS - 1) {
                    const _Float16* r = inb + (k + 1) * HROW;
                    vi0 = ((const h8*)r)[0]; vi1 = ((const h8*)r)[1];
                    vi2 = ((const h8*)r)[2]; vi3 = ((const h8*)r)[3];
                    vit = *(const h2*)(r + 32);
                }
                // tail (R4-proven numerics)
                const float ig = sigm_f(a0);
                const float fg = sigm_f(a1);
                const float gg = tanh_f(a2);
                const float og = sigm_f(a3);
                c = __builtin_fmaf(fg, c, ig * gg);
                const float hnew = og * tanh_f(c);
                const _Float16 h16 = (_Float16)hnew;
                if (cl) {
                    hop[j] = h16;                         // own-h broadcast slot
                    if (haveout) ob[k * HROW + j] = h16;  // handoff to layer l+1
                }
                if (k == SS - 1 && last && cl) {
                    hidden_out[((size_t)wid * BB + bg) * HH + j] = hnew;
                    hfin[wid][j] = hnew;
                }
                // reload own-h for next step (in-order DS: sees this step's writes)
                if (k < SS - 1) {
                    vo0 = ((const h8*)hop)[0]; vo1 = ((const h8*)hop)[1];
                    vo2 = ((const h8*)hop)[2]; vo3 = ((const h8*)hop)[3];
                    vot = *(const h2*)(hop + 32);
                }
            };
            step(0); step(1); step(2); step(3);
            step(4); step(5); step(6); step(7);
        }

        // C) land prefetched x into the other parity buffer (vmcnt drains here,
        //    once per epoch -- off the step critical path)
        if (pf) {
            _Float16* xw = &xbuf[par ^ 1][0][0];
            #pragma unroll
            for (int q = 0; q < 4; ++q) {
                const int f = 4 * pl + q;
                const int t = (f * 373) >> 12;
                const int i = f - 11 * t;
                xw[t * HROW + i] = (_Float16)((&pv.x)[q]);
            }
        }
        __syncthreads();
    }

    // ---- fused MLP head (hfin complete after the final barrier) ----
    if (tid < 4 * OO) {                   // 72 threads x 3 layers
        #pragma unroll
        for (int ml = 0; ml < NL; ++ml) {
            float a = b1[tid];
            #pragma unroll
            for (int k = 0; k < HH; ++k) a += hfin[ml][k] * W1[tid * HH + k];
            h1s[ml][tid] = 0.5f * a * (1.0f + erff(a * 0.70710678118654752f));
        }
    }
    __syncthreads();
    if (tid < NL * OO) {                  // 54 threads
        const int ol = tid / OO, o = tid % OO;
        float a = b2[o];
        #pragma unroll
        for (int m = 0; m < 4 * OO; ++m) a += h1s[ol][m] * W2[o * (4 * OO) + m];
        outp[((size_t)ol * BB + bg) * OO + o] = a;
    }
}

extern "C" void kernel_launch(void* const* d_in, const int* in_sizes, int n_in,
                              void* d_out, int out_size, void* d_ws, size_t ws_size,
                              hipStream_t stream) {
    const float* x    = (const float*)d_in[0];
    const float* Wih0 = (const float*)d_in[1];
    const float* Whh0 = (const float*)d_in[2];
    const float* bih0 = (const float*)d_in[3];
    const float* bhh0 = (const float*)d_in[4];
    const float* Wih1 = (const float*)d_in[5];
    const float* Whh1 = (const float*)d_in[6];
    const float* bih1 = (const float*)d_in[7];
    const float* bhh1 = (const float*)d_in[8];
    const float* Wih2 = (const float*)d_in[9];
    const float* Whh2 = (const float*)d_in[10];
    const float* bih2 = (const float*)d_in[11];
    const float* bhh2 = (const float*)d_in[12];
    const float* W1   = (const float*)d_in[13];
    const float* b1   = (const float*)d_in[14];
    const float* W2   = (const float*)d_in[15];
    const float* b2   = (const float*)d_in[16];

    float* out    = (float*)d_out;                 // [3,512,18] = 27648 floats
    float* hidden = out + NL * BB * OO;            // [3,512,33] = 50688 floats

    lstm_epoch_kernel<<<BB, 192, 0, stream>>>(
        x, Wih0, Whh0, bih0, bhh0, Wih1, Whh1, bih1, bhh1,
        Wih2, Whh2, bih2, bhh2, W1, b1, W2, b2, hidden, out);
}

// Round 8
// 1797.616 us; speedup vs baseline: 1.0340x; 1.0340x over previous
//
#include <hip/hip_runtime.h>
#include <math.h>

// Problem constants (from reference)
#define TT 2048
#define BB 512
#define II 11
#define HH 33
#define NL 3
#define OO 18
#define HSLOT 48          // halves per LDS vector slot (96 B, 16B-aligned slots)
#define XPAD 16           // halves per staged-x row (32 B, b128-aligned reads)

typedef _Float16 h2 __attribute__((ext_vector_type(2)));
typedef _Float16 h8 __attribute__((ext_vector_type(8)));   // 16 B -> ds_read_b128

// fast sigmoid / tanh via v_exp_f32 + v_rcp_f32 (saturate correctly at +-inf)
__device__ __forceinline__ float sigm_f(float x) {
    float e = __expf(-x);
    return __builtin_amdgcn_rcpf(1.0f + e);
}
__device__ __forceinline__ float tanh_f(float x) {
    float e = __expf(2.0f * x);
    return 1.0f - 2.0f * __builtin_amdgcn_rcpf(e + 1.0f);
}

// guarded fp32->fp16 row-slice loads (zero-pad past rem)
__device__ __forceinline__ h8 gldh8(const float* p, int k0, int rem) {
    h8 v;
    #pragma unroll
    for (int i = 0; i < 8; ++i) v[i] = (_Float16)((k0 + i < rem) ? p[k0 + i] : 0.0f);
    return v;
}
__device__ __forceinline__ h2 gldh2(const float* p, int k0, int rem) {
    h2 v;
    v.x = (_Float16)((k0 + 0 < rem) ? p[k0 + 0] : 0.0f);
    v.y = (_Float16)((k0 + 1 < rem) ? p[k0 + 1] : 0.0f);
    return v;
}

// v_dot2_f32_f16: 2 MACs/op, fp32 accumulate
#define FD(a, p, q) a = __builtin_amdgcn_fdot2((p), (q), a, false)
// one 2-half slice fed to all 8 chains (4 input-side + 4 own-h-side)
#define DUO(vi_, vo_, SEL) do { \
    FD(a0i, (vi_).SEL, (xw0).SEL); FD(a1i, (vi_).SEL, (xw1).SEL); \
    FD(a2i, (vi_).SEL, (xw2).SEL); FD(a3i, (vi_).SEL, (xw3).SEL); \
    FD(a0h, (vo_).SEL, (hw0).SEL); FD(a1h, (vo_).SEL, (hw1).SEL); \
    FD(a2h, (vo_).SEL, (hw2).SEL); FD(a3h, (vo_).SEL, (hw3).SEL); } while (0)
#define DUOQ(vi_, vo_, xq0, xq1, xq2, xq3, hq0, hq1, hq2, hq3) do { \
    const h8 xw0 = (xq0), xw1 = (xq1), xw2 = (xq2), xw3 = (xq3); \
    const h8 hw0 = (hq0), hw1 = (hq1), hw2 = (hq2), hw3 = (hq3); \
    DUO(vi_, vo_, s01); DUO(vi_, vo_, s23); \
    DUO(vi_, vo_, s45); DUO(vi_, vo_, s67); } while (0)

// DUAL-BATCH layer-pipelined LSTM, ONE LANE PER UNIT, fused MLP head.
// grid = 256 blocks; each block runs TWO batch elements (bg, bg+256) in the
// SAME lanes, sharing the 136 weight VGPRs. Cross-round ledger (R0-R7):
// per-step time = ~400 cy wave issue + ~800 cy latency (ds_read ~160, serial
// trans tail ~200, write/drain/barrier ~150+) that NOTHING overlaps -- not
// co-resident blocks (R1/R3), not barrier removal (R7). The only thing that
// can fill a wave's stall is independent work in the SAME wave: batch B's
// dot issue hides batch A's tail/read latency and vice versa. One barrier/
// tail/read structure now serves two timestep-advances.
// block = 128 threads (2 waves), 1 block/CU (LDS 135 KB -- deliberate; extra
// occupancy is proven worthless here). tid<99: unit u=tid, l=u/33, j=u%33;
// per step: A-vecs -> A-dots (8x17 fdot2 chains) -> B-vecs -> B-dots ->
// A-tail -> B-tail -> h writes -> barrier. Zero global ops in the loop
// (both batches' x fully staged in LDS, R6 scheme).
__global__ __launch_bounds__(128, 1) void lstm_pipeline_kernel(
    const float* __restrict__ x,
    const float* __restrict__ Wih0, const float* __restrict__ Whh0,
    const float* __restrict__ bih0, const float* __restrict__ bhh0,
    const float* __restrict__ Wih1, const float* __restrict__ Whh1,
    const float* __restrict__ bih1, const float* __restrict__ bhh1,
    const float* __restrict__ Wih2, const float* __restrict__ Whh2,
    const float* __restrict__ bih2, const float* __restrict__ bhh2,
    const float* __restrict__ W1, const float* __restrict__ b1,
    const float* __restrict__ W2, const float* __restrict__ b2,
    float* __restrict__ hidden_out,   // [3, 512, 33]
    float* __restrict__ outp)         // [3, 512, 18]
{
    __shared__ __align__(16) _Float16 xst[2][TT + 2][XPAD];      // 131.2 KB
    __shared__ __align__(16) _Float16 buf[2][2][NL + 1][HSLOT];  // [bb][par]
    __shared__ float hfin[2][NL][HH + 1];
    __shared__ float h1s[2][NL][4 * OO];

    const int tid = threadIdx.x;
    const int bgA = blockIdx.x;
    const int bgB = blockIdx.x + 256;

    for (int i = tid; i < 2 * 2 * (NL + 1) * HSLOT; i += 128)
        ((_Float16*)buf)[i] = (_Float16)0.0f;

    // ---- x staging for BOTH batches: pad cells zeroed, real cells filled ----
    for (int f = tid; f < 2 * (TT + 2) * XPAD; f += 128) {
        const int i = f & (XPAD - 1);
        int t = f >> 4;
        if (t >= (TT + 2)) t -= (TT + 2);
        if (i >= II || t >= TT) ((_Float16*)xst)[f] = (_Float16)0.0f;
    }
    #pragma unroll
    for (int bb = 0; bb < 2; ++bb) {
        const float* xblk = x + (size_t)(bb ? bgB : bgA) * TT * II;
        const float4* xf4 = (const float4*)xblk;      // 22528 floats = 5632 f4
        for (int f4 = tid; f4 < (TT * II) / 4; f4 += 128) {
            const float4 v = xf4[f4];
            const int e0 = 4 * f4;
            #pragma unroll
            for (int e = 0; e < 4; ++e) {
                const int idx = e0 + e;
                const int t = idx / II;               // magic-mul
                const int i = idx - t * II;
                xst[bb][t][i] = (_Float16)((&v.x)[e]);
            }
        }
    }

    const bool comp = (tid < 99);
    const int  u    = tid;
    const int  l    = (u < 33) ? 0 : (u < 66) ? 1 : 2;
    const int  j    = u - 33 * l;

    // ---- per-lane weights (SHARED by both batches): 4 gates x 2 sides ----
    h8 z8 = {0,0,0,0,0,0,0,0};
    h2 z2 = {(_Float16)0.0f, (_Float16)0.0f};
    h8 x00=z8,x01=z8,x02=z8,x03=z8; h2 x0t=z2;   // gate i, input side
    h8 x10=z8,x11=z8,x12=z8,x13=z8; h2 x1t=z2;   // gate f
    h8 x20=z8,x21=z8,x22=z8,x23=z8; h2 x2t=z2;   // gate g
    h8 x30=z8,x31=z8,x32=z8,x33=z8; h2 x3t=z2;   // gate o
    h8 h00=z8,h01=z8,h02=z8,h03=z8; h2 h0t=z2;   // own-h side
    h8 h10=z8,h11=z8,h12=z8,h13=z8; h2 h1t=z2;
    h8 h20=z8,h21=z8,h22=z8,h23=z8; h2 h2t=z2;
    h8 h30=z8,h31=z8,h32=z8,h33=z8; h2 h3t=z2;
    float b0 = 0.0f, b1v = 0.0f, b2v = 0.0f, b3v = 0.0f;

    if (comp) {
        const float* bip = (l == 0) ? bih0 : (l == 1) ? bih1 : bih2;
        const float* bhp = (l == 0) ? bhh0 : (l == 1) ? bhh1 : bhh2;
        b0  = bip[0 * HH + j] + bhp[0 * HH + j];
        b1v = bip[1 * HH + j] + bhp[1 * HH + j];
        b2v = bip[2 * HH + j] + bhp[2 * HH + j];
        b3v = bip[3 * HH + j] + bhp[3 * HH + j];

        const float* Wi = (l == 0) ? Wih0 : (l == 1) ? Wih1 : Wih2;
        const float* Wh = (l == 0) ? Whh0 : (l == 1) ? Whh1 : Whh2;
        const int kin = (l == 0) ? II : HH;
        const float* r0 = Wi + (0 * HH + j) * kin;
        const float* r1 = Wi + (1 * HH + j) * kin;
        const float* r2 = Wi + (2 * HH + j) * kin;
        const float* r3 = Wi + (3 * HH + j) * kin;
        x00=gldh8(r0,0,kin); x01=gldh8(r0,8,kin); x02=gldh8(r0,16,kin); x03=gldh8(r0,24,kin); x0t=gldh2(r0,32,kin);
        x10=gldh8(r1,0,kin); x11=gldh8(r1,8,kin); x12=gldh8(r1,16,kin); x13=gldh8(r1,24,kin); x1t=gldh2(r1,32,kin);
        x20=gldh8(r2,0,kin); x21=gldh8(r2,8,kin); x22=gldh8(r2,16,kin); x23=gldh8(r2,24,kin); x2t=gldh2(r2,32,kin);
        x30=gldh8(r3,0,kin); x31=gldh8(r3,8,kin); x32=gldh8(r3,16,kin); x33=gldh8(r3,24,kin); x3t=gldh2(r3,32,kin);
        const float* s0 = Wh + (0 * HH + j) * HH;
        const float* s1 = Wh + (1 * HH + j) * HH;
        const float* s2 = Wh + (2 * HH + j) * HH;
        const float* s3 = Wh + (3 * HH + j) * HH;
        h00=gldh8(s0,0,HH); h01=gldh8(s0,8,HH); h02=gldh8(s0,16,HH); h03=gldh8(s0,24,HH); h0t=gldh2(s0,32,HH);
        h10=gldh8(s1,0,HH); h11=gldh8(s1,8,HH); h12=gldh8(s1,16,HH); h13=gldh8(s1,24,HH); h1t=gldh2(s1,32,HH);
        h20=gldh8(s2,0,HH); h21=gldh8(s2,8,HH); h22=gldh8(s2,16,HH); h23=gldh8(s2,24,HH); h2t=gldh2(s2,32,HH);
        h30=gldh8(s3,0,HH); h31=gldh8(s3,8,HH); h32=gldh8(s3,16,HH); h33=gldh8(s3,24,HH); h3t=gldh2(s3,32,HH);
    }

    __syncthreads();

    float cA = 0.0f, cB = 0.0f;

    // hoisted ping-pong pointers (compile-time selected in peeled steps)
    const _Float16* rinA[2]  = { &buf[0][0][l][0],     &buf[0][1][l][0] };
    const _Float16* rownA[2] = { &buf[0][0][l + 1][0], &buf[0][1][l + 1][0] };
    _Float16*       wrpA[2]  = { &buf[0][0][l + 1][j], &buf[0][1][l + 1][j] };
    const _Float16* rinB[2]  = { &buf[1][0][l][0],     &buf[1][1][l][0] };
    const _Float16* rownB[2] = { &buf[1][0][l + 1][0], &buf[1][1][l + 1][0] };
    _Float16*       wrpB[2]  = { &buf[1][0][l + 1][j], &buf[1][1][l + 1][j] };
    const _Float16* xstA = &xst[0][0][0];
    const _Float16* xstB = &xst[1][0][0];

    // one superstep (TWO batch advances); rp/check/out compile-time constants
    auto step = [&](int s, int rp, bool check, bool out)
        __attribute__((always_inline)) {
        const int wp = rp ^ 1;
        const bool active = check ? (comp && (s >= l) && (s - l < TT)) : comp;
        if (active) {
            float sA0, sA1, sA2, sA3, sB0, sB1, sB2, sB3;
            {   // ---- batch A: vectors + dots ----
                const _Float16* ri = (l == 0) ? (xstA + (s << 4)) : rinA[rp];
                const h8* VI = (const h8*)ri;
                const h8 vi0 = VI[0], vi1 = VI[1], vi2 = VI[2], vi3 = VI[3];
                const h2 vit = *(const h2*)(ri + 32);
                const h8* VO = (const h8*)rownA[rp];
                const h8 vo0 = VO[0], vo1 = VO[1], vo2 = VO[2], vo3 = VO[3];
                const h2 vot = *(const h2*)(rownA[rp] + 32);
                float a0i = b0, a1i = b1v, a2i = b2v, a3i = b3v;
                float a0h = 0.0f, a1h = 0.0f, a2h = 0.0f, a3h = 0.0f;
                DUOQ(vi0, vo0, x00, x10, x20, x30, h00, h10, h20, h30);
                DUOQ(vi1, vo1, x01, x11, x21, x31, h01, h11, h21, h31);
                DUOQ(vi2, vo2, x02, x12, x22, x32, h02, h12, h22, h32);
                DUOQ(vi3, vo3, x03, x13, x23, x33, h03, h13, h23, h33);
                FD(a0i, vit, x0t); FD(a1i, vit, x1t);
                FD(a2i, vit, x2t); FD(a3i, vit, x3t);
                FD(a0h, vot, h0t); FD(a1h, vot, h1t);
                FD(a2h, vot, h2t); FD(a3h, vot, h3t);
                sA0 = a0i + a0h; sA1 = a1i + a1h;
                sA2 = a2i + a2h; sA3 = a3i + a3h;
            }
            {   // ---- batch B: vectors + dots (hides A-tail latency) ----
                const _Float16* ri = (l == 0) ? (xstB + (s << 4)) : rinB[rp];
                const h8* VI = (const h8*)ri;
                const h8 vi0 = VI[0], vi1 = VI[1], vi2 = VI[2], vi3 = VI[3];
                const h2 vit = *(const h2*)(ri + 32);
                const h8* VO = (const h8*)rownB[rp];
                const h8 vo0 = VO[0], vo1 = VO[1], vo2 = VO[2], vo3 = VO[3];
                const h2 vot = *(const h2*)(rownB[rp] + 32);
                float a0i = b0, a1i = b1v, a2i = b2v, a3i = b3v;
                float a0h = 0.0f, a1h = 0.0f, a2h = 0.0f, a3h = 0.0f;
                DUOQ(vi0, vo0, x00, x10, x20, x30, h00, h10, h20, h30);
                DUOQ(vi1, vo1, x01, x11, x21, x31, h01, h11, h21, h31);
                DUOQ(vi2, vo2, x02, x12, x22, x32, h02, h12, h22, h32);
                DUOQ(vi3, vo3, x03, x13, x23, x33, h03, h13, h23, h33);
                FD(a0i, vit, x0t); FD(a1i, vit, x1t);
                FD(a2i, vit, x2t); FD(a3i, vit, x3t);
                FD(a0h, vot, h0t); FD(a1h, vot, h1t);
                FD(a2h, vot, h2t); FD(a3h, vot, h3t);
                sB0 = a0i + a0h; sB1 = a1i + a1h;
                sB2 = a2i + a2h; sB3 = a3i + a3h;
            }
            // ---- tails: two independent trans/c/h chains (latency overlaps) ----
            const float igA = sigm_f(sA0);
            const float fgA = sigm_f(sA1);
            const float ggA = tanh_f(sA2);
            const float ogA = sigm_f(sA3);
            const float igB = sigm_f(sB0);
            const float fgB = sigm_f(sB1);
            const float ggB = tanh_f(sB2);
            const float ogB = sigm_f(sB3);
            cA = __builtin_fmaf(fgA, cA, igA * ggA);
            cB = __builtin_fmaf(fgB, cB, igB * ggB);
            const float hA = ogA * tanh_f(cA);
            const float hB = ogB * tanh_f(cB);

            *wrpA[wp] = (_Float16)hA;
            *wrpB[wp] = (_Float16)hB;
            if (out && (s - l == TT - 1)) {
                hidden_out[((size_t)l * BB + bgA) * HH + j] = hA;
                hidden_out[((size_t)l * BB + bgB) * HH + j] = hB;
                hfin[0][l][j] = hA;
                hfin[1][l][j] = hB;
            }
        }
        __syncthreads();
    };

    // prologue (pipeline fill, masked)
    step(0, 0, true, false);
    step(1, 1, true, false);
    // steady state: s = 2..2043 as constant-rp pairs (no checks, no outputs)
    for (int s = 2; s < TT - 4; s += 2) {
        step(s,     0, false, false);
        step(s + 1, 1, false, false);
    }
    // tail of steady state + epilogue (drain + final-h outputs)
    step(TT - 4, 0, false, false);   // s=2044
    step(TT - 3, 1, false, false);   // s=2045
    step(TT - 2, 0, false, false);   // s=2046
    step(TT - 1, 1, false, true);    // s=2047: l0 writes hT
    step(TT,     0, true,  true);    // s=2048: l1 writes hT
    step(TT + 1, 1, true,  true);    // s=2049: l2 writes hT

    // ---- fused MLP head, both batches ----
    if (tid < 4 * OO) {                   // 72 threads x 3 layers x 2 batches
        #pragma unroll
        for (int bb = 0; bb < 2; ++bb) {
            #pragma unroll
            for (int ml = 0; ml < NL; ++ml) {
                float a = b1[tid];
                #pragma unroll
                for (int k = 0; k < HH; ++k) a += hfin[bb][ml][k] * W1[tid * HH + k];
                h1s[bb][ml][tid] = 0.5f * a * (1.0f + erff(a * 0.70710678118654752f));
            }
        }
    }
    __syncthreads();
    if (tid < NL * OO) {                  // 54 threads x 2 batches
        const int ol = tid / OO, o = tid % OO;
        #pragma unroll
        for (int bb = 0; bb < 2; ++bb) {
            float a = b2[o];
            #pragma unroll
            for (int m = 0; m < 4 * OO; ++m) a += h1s[bb][ol][m] * W2[o * (4 * OO) + m];
            outp[((size_t)ol * BB + (bb ? bgB : bgA)) * OO + o] = a;
        }
    }
}

extern "C" void kernel_launch(void* const* d_in, const int* in_sizes, int n_in,
                              void* d_out, int out_size, void* d_ws, size_t ws_size,
                              hipStream_t stream) {
    const float* x    = (const float*)d_in[0];
    const float* Wih0 = (const float*)d_in[1];
    const float* Whh0 = (const float*)d_in[2];
    const float* bih0 = (const float*)d_in[3];
    const float* bhh0 = (const float*)d_in[4];
    const float* Wih1 = (const float*)d_in[5];
    const float* Whh1 = (const float*)d_in[6];
    const float* bih1 = (const float*)d_in[7];
    const float* bhh1 = (const float*)d_in[8];
    const float* Wih2 = (const float*)d_in[9];
    const float* Whh2 = (const float*)d_in[10];
    const float* bih2 = (const float*)d_in[11];
    const float* bhh2 = (const float*)d_in[12];
    const float* W1   = (const float*)d_in[13];
    const float* b1   = (const float*)d_in[14];
    const float* W2   = (const float*)d_in[15];
    const float* b2   = (const float*)d_in[16];

    float* out    = (float*)d_out;                 // [3,512,18] = 27648 floats
    float* hidden = out + NL * BB * OO;            // [3,512,33] = 50688 floats

    lstm_pipeline_kernel<<<BB / 2, 128, 0, stream>>>(
        x, Wih0, Whh0, bih0, bhh0, Wih1, Whh1, bih1, bhh1,
        Wih2, Whh2, bih2, bhh2, W1, b1, W2, b2, hidden, out);
}